// Round 2
// baseline (436.451 us; speedup 1.0000x reference)
//
#include <hip/hip_runtime.h>
#include <hip/hip_bf16.h>
#include <cstdint>

#define T_TOK 8192
#define HID   1024
#define NE    9      // 8 routed experts + 1 shared (e=8, weight 1.0)
#define ISZ   512
#define ECAP  8192   // per-expert bucket capacity

#define BM 128
#define BN 128
#define BK 32

typedef unsigned short u16;
typedef unsigned int   u32;
typedef __attribute__((ext_vector_type(8))) short short8;
typedef __attribute__((ext_vector_type(4))) float f32x4;

__device__ __forceinline__ u16 f2bf(float f) {
  u32 u = __builtin_bit_cast(u32, f);
  return (u16)((u + 0x7fffu + ((u >> 16) & 1u)) >> 16);
}

#define STAGE(gp, lp) __builtin_amdgcn_global_load_lds( \
    (__attribute__((address_space(1))) u32*)(gp),       \
    (__attribute__((address_space(3))) u32*)(lp), 16, 0, 0)

// ---------------- conversions ----------------
__global__ void k_cvt_x(const float* __restrict__ x, u16* __restrict__ xb, int n4) {
  int i = blockIdx.x * blockDim.x + threadIdx.x;
  if (i >= n4) return;
  float4 v = ((const float4*)x)[i];
  ushort4 o;
  o.x = f2bf(v.x); o.y = f2bf(v.y); o.z = f2bf(v.z); o.w = f2bf(v.w);
  ((ushort4*)xb)[i] = o;
}

// w_experts_gate_up [8][1024][1024] + w_shared_gate_up [1024][1024]
// -> dst [9][1024(colp)][1024(h)]  (transposed, gate/up interleaved per 16 cols)
__global__ void k_cvt_wgup(const float* __restrict__ wexp, const float* __restrict__ wsh,
                           u16* __restrict__ dst) {
  __shared__ float tile[32][33];
  const int e = blockIdx.z;
  const float* src = (e < 8) ? (wexp + (size_t)e * HID * 1024) : wsh;
  const int c0 = blockIdx.x * 32, h0 = blockIdx.y * 32;
  const int tx = threadIdx.x, ty = threadIdx.y;
  for (int i = ty; i < 32; i += 8)
    tile[i][tx] = src[(size_t)(h0 + i) * 1024 + c0 + tx];   // tile[h_loc][c_loc]
  __syncthreads();
  for (int j = ty; j < 32; j += 8) {
    int c = c0 + j;
    int i = (c < 512) ? c : (c - 512);
    int colp = ((i >> 4) * 32) + ((c < 512) ? 0 : 16) + (i & 15);
    dst[((size_t)e * 1024 + colp) * HID + h0 + tx] = f2bf(tile[tx][j]);
  }
}

// w_experts_down [8][512][1024] + w_shared_down [512][1024]
// -> dst [9][1024(h_out)][512(i)]  (transposed)
__global__ void k_cvt_wdown(const float* __restrict__ wexp, const float* __restrict__ wsh,
                            u16* __restrict__ dst) {
  __shared__ float tile[32][33];
  const int e = blockIdx.z;
  const float* src = (e < 8) ? (wexp + (size_t)e * ISZ * HID) : wsh;
  const int h0 = blockIdx.x * 32, i0 = blockIdx.y * 32;
  const int tx = threadIdx.x, ty = threadIdx.y;
  for (int a = ty; a < 32; a += 8)
    tile[a][tx] = src[(size_t)(i0 + a) * HID + h0 + tx];    // tile[i_loc][h_loc]
  __syncthreads();
  for (int j = ty; j < 32; j += 8)
    dst[((size_t)e * HID + h0 + j) * ISZ + i0 + tx] = f2bf(tile[tx][j]);
}

// ---------------- router + bucketing ----------------
__global__ void k_zero_counts(int* counts) {
  if (threadIdx.x < 8) counts[threadIdx.x] = 0;
}

__global__ void k_router(const float* __restrict__ x, const float* __restrict__ wg,
                         int* __restrict__ counts, int* __restrict__ btok,
                         float* __restrict__ bw) {
  const int t = blockIdx.x;
  const int l = threadIdx.x;
  float a[8] = {0, 0, 0, 0, 0, 0, 0, 0};
  const float* xr = x + (size_t)t * HID;
#pragma unroll
  for (int j = 0; j < HID / 64; ++j) {
    const int h = j * 64 + l;
    const float xv = xr[h];
    const float4 w0 = *(const float4*)&wg[h * 8];
    const float4 w1 = *(const float4*)&wg[h * 8 + 4];
    a[0] += xv * w0.x; a[1] += xv * w0.y; a[2] += xv * w0.z; a[3] += xv * w0.w;
    a[4] += xv * w1.x; a[5] += xv * w1.y; a[6] += xv * w1.z; a[7] += xv * w1.w;
  }
#pragma unroll
  for (int off = 32; off >= 1; off >>= 1) {
#pragma unroll
    for (int e2 = 0; e2 < 8; ++e2) a[e2] += __shfl_xor(a[e2], off);
  }
  if (l == 0) {
    int ia = 0;
#pragma unroll
    for (int e2 = 1; e2 < 8; ++e2) if (a[e2] > a[ia]) ia = e2;
    int ib = (ia == 0) ? 1 : 0;
#pragma unroll
    for (int e2 = 0; e2 < 8; ++e2) if (e2 != ia && a[e2] > a[ib]) ib = e2;
    float wa = 1.f / (1.f + __expf(a[ib] - a[ia]));  // renormalized softmax top-2
    float wb = 1.f - wa;
    int pa = atomicAdd(&counts[ia], 1);
    btok[ia * ECAP + pa] = t;
    bw[ia * ECAP + pa] = wa;
    int pb = atomicAdd(&counts[ib], 1);
    btok[ib * ECAP + pb] = t;
    bw[ib * ECAP + pb] = wb;
  }
}

// ---------------- GEMM1: act[e][slot] = silu(g)*u * w  (A gathered by token) ----
__global__ __launch_bounds__(256) void k_gemm_gu(
    const u16* __restrict__ xb,     // [T][H] bf16
    const u16* __restrict__ wgupT,  // [NE][1024][H] bf16 (B^T, interleaved cols)
    const int* __restrict__ counts,
    const int* __restrict__ btok,   // [8][ECAP]
    const float* __restrict__ bw,   // [8][ECAP]
    u16* __restrict__ act)          // [NE][ECAP][ISZ] bf16 (pre-scaled)
{
  const int e = blockIdx.z;
  const int cnt = (e < 8) ? counts[e] : T_TOK;
  const int brow = blockIdx.x * BM;
  if (brow >= cnt) return;

  __shared__ __align__(16) u16 As[BM * BK];
  __shared__ __align__(16) u16 Bs[BN * BK];
  __shared__ float cws[BM];

  const int tid = threadIdx.x;
  const int w = tid >> 6, l = tid & 63;
  const int bcol = blockIdx.y * BN;

  if (tid < BM) {
    int rr = brow + tid;
    cws[tid] = (e < 8) ? ((rr < cnt) ? bw[e * ECAP + rr] : 0.f) : 1.f;
  }

  const int sub = l >> 2;        // row within 16-row chunk
  const int kc  = (l & 3) * 8;   // k element offset

  const int r0 = brow + (w * 2 + 0) * 16 + sub;
  const int r1 = brow + (w * 2 + 1) * 16 + sub;
  const int t0 = (e < 8) ? ((r0 < cnt) ? btok[e * ECAP + r0] : 0) : r0;
  const int t1 = (e < 8) ? ((r1 < cnt) ? btok[e * ECAP + r1] : 0) : r1;

  const u16* ga0 = xb + (size_t)t0 * HID + kc;
  const u16* ga1 = xb + (size_t)t1 * HID + kc;
  const u16* gb0 = wgupT + ((size_t)e * 1024 + bcol + (w * 2 + 0) * 16 + sub) * HID + kc;
  const u16* gb1 = wgupT + ((size_t)e * 1024 + bcol + (w * 2 + 1) * 16 + sub) * HID + kc;

  u16* la0 = &As[(w * 2 + 0) * 16 * BK];
  u16* la1 = &As[(w * 2 + 1) * 16 * BK];
  u16* lb0 = &Bs[(w * 2 + 0) * 16 * BK];
  u16* lb1 = &Bs[(w * 2 + 1) * 16 * BK];

  const int wm = w >> 1, wn = w & 1;
  const int fr = l & 15, fg = l >> 4;

  f32x4 acc[4][4];
#pragma unroll
  for (int m = 0; m < 4; ++m)
#pragma unroll
    for (int n = 0; n < 4; ++n) acc[m][n] = (f32x4){0.f, 0.f, 0.f, 0.f};

  for (int kt = 0; kt < HID / BK; ++kt) {
    const int ko = kt * BK;
    STAGE(ga0 + ko, la0);
    STAGE(ga1 + ko, la1);
    STAGE(gb0 + ko, lb0);
    STAGE(gb1 + ko, lb1);
    __syncthreads();
    short8 af[4], bfr[4];
#pragma unroll
    for (int m = 0; m < 4; ++m)
      af[m] = *(const short8*)&As[(wm * 64 + m * 16 + fr) * BK + fg * 8];
#pragma unroll
    for (int n = 0; n < 4; ++n)
      bfr[n] = *(const short8*)&Bs[(wn * 64 + n * 16 + fr) * BK + fg * 8];
#pragma unroll
    for (int m = 0; m < 4; ++m)
#pragma unroll
      for (int n = 0; n < 4; ++n)
        acc[m][n] = __builtin_amdgcn_mfma_f32_16x16x32_bf16(af[m], bfr[n], acc[m][n], 0, 0, 0);
    __syncthreads();
  }

  // epilogue: pair adjacent 16-col fragments (gate, up), silu*up*w -> act bf16
#pragma unroll
  for (int m = 0; m < 4; ++m) {
#pragma unroll
    for (int p = 0; p < 2; ++p) {
      f32x4 g = acc[m][2 * p], u = acc[m][2 * p + 1];
      const int ab = blockIdx.y * 4 + wn * 2 + p;  // act 16-col block
      const int col = ab * 16 + fr;
#pragma unroll
      for (int r = 0; r < 4; ++r) {
        const int row_l = wm * 64 + m * 16 + fg * 4 + r;
        float gate = g[r], u2 = u[r];
        float s = gate / (1.f + expf(-gate));
        float val = s * u2 * cws[row_l];
        act[((size_t)e * ECAP + brow + row_l) * ISZ + col] = f2bf(val);
      }
    }
  }
}

// ---------------- GEMM2 core (K = 512) ----------------
template <bool SHARED>
__device__ __forceinline__ void gemm_down_body(
    const u16* __restrict__ act, const u16* __restrict__ wdT,
    const int* __restrict__ counts, const int* __restrict__ btok,
    float* __restrict__ out, int e, int brow, int bcol) {
  __shared__ __align__(16) u16 As[BM * BK];
  __shared__ __align__(16) u16 Bs[BN * BK];

  const int tid = threadIdx.x;
  const int w = tid >> 6, l = tid & 63;
  const int sub = l >> 2;
  const int kc  = (l & 3) * 8;

  const u16* pa0 = act + ((size_t)e * ECAP + brow + (w * 2 + 0) * 16 + sub) * ISZ + kc;
  const u16* pa1 = act + ((size_t)e * ECAP + brow + (w * 2 + 1) * 16 + sub) * ISZ + kc;
  const u16* pb0 = wdT + ((size_t)e * HID + bcol + (w * 2 + 0) * 16 + sub) * ISZ + kc;
  const u16* pb1 = wdT + ((size_t)e * HID + bcol + (w * 2 + 1) * 16 + sub) * ISZ + kc;

  u16* la0 = &As[(w * 2 + 0) * 16 * BK];
  u16* la1 = &As[(w * 2 + 1) * 16 * BK];
  u16* lb0 = &Bs[(w * 2 + 0) * 16 * BK];
  u16* lb1 = &Bs[(w * 2 + 1) * 16 * BK];

  const int wm = w >> 1, wn = w & 1;
  const int fr = l & 15, fg = l >> 4;

  f32x4 acc[4][4];
#pragma unroll
  for (int m = 0; m < 4; ++m)
#pragma unroll
    for (int n = 0; n < 4; ++n) acc[m][n] = (f32x4){0.f, 0.f, 0.f, 0.f};

  for (int kt = 0; kt < ISZ / BK; ++kt) {   // 16 iters
    const int ko = kt * BK;
    STAGE(pa0 + ko, la0);
    STAGE(pa1 + ko, la1);
    STAGE(pb0 + ko, lb0);
    STAGE(pb1 + ko, lb1);
    __syncthreads();
    short8 af[4], bfr[4];
#pragma unroll
    for (int m = 0; m < 4; ++m)
      af[m] = *(const short8*)&As[(wm * 64 + m * 16 + fr) * BK + fg * 8];
#pragma unroll
    for (int n = 0; n < 4; ++n)
      bfr[n] = *(const short8*)&Bs[(wn * 64 + n * 16 + fr) * BK + fg * 8];
#pragma unroll
    for (int m = 0; m < 4; ++m)
#pragma unroll
      for (int n = 0; n < 4; ++n)
        acc[m][n] = __builtin_amdgcn_mfma_f32_16x16x32_bf16(af[m], bfr[n], acc[m][n], 0, 0, 0);
    __syncthreads();
  }

  const int cnt = SHARED ? T_TOK : counts[e];
#pragma unroll
  for (int m = 0; m < 4; ++m) {
#pragma unroll
    for (int r = 0; r < 4; ++r) {
      const int slot = brow + wm * 64 + m * 16 + fg * 4 + r;
      if (slot >= cnt) continue;
      const int tok = SHARED ? slot : btok[e * ECAP + slot];
      float* orow = out + (size_t)tok * HID + bcol + wn * 64 + fr;
#pragma unroll
      for (int n = 0; n < 4; ++n) {
        if (SHARED) orow[n * 16] = acc[m][n][r];
        else        atomicAdd(&orow[n * 16], acc[m][n][r]);
      }
    }
  }
}

__global__ __launch_bounds__(256) void k_gemm_down_s(
    const u16* __restrict__ act, const u16* __restrict__ wdT, float* __restrict__ out) {
  gemm_down_body<true>(act, wdT, nullptr, nullptr, out, 8,
                       blockIdx.x * BM, blockIdx.y * BN);
}

__global__ __launch_bounds__(256) void k_gemm_down_r(
    const u16* __restrict__ act, const u16* __restrict__ wdT,
    const int* __restrict__ counts, const int* __restrict__ btok,
    float* __restrict__ out) {
  const int e = blockIdx.z;
  const int brow = blockIdx.x * BM;
  if (brow >= counts[e]) return;
  gemm_down_body<false>(act, wdT, counts, btok, out, e, brow, blockIdx.y * BN);
}

// ---------------- launch ----------------
extern "C" void kernel_launch(void* const* d_in, const int* in_sizes, int n_in,
                              void* d_out, int out_size, void* d_ws, size_t ws_size,
                              hipStream_t stream) {
  const float* x   = (const float*)d_in[0];
  const float* wg  = (const float*)d_in[1];
  const float* wgu = (const float*)d_in[2];
  const float* wdn = (const float*)d_in[3];
  const float* wsg = (const float*)d_in[4];
  const float* wsd = (const float*)d_in[5];
  float* out = (float*)d_out;

  char* ws = (char*)d_ws;
  u16* xb    = (u16*)ws;  ws += (size_t)T_TOK * HID * 2;
  u16* wgupT = (u16*)ws;  ws += (size_t)NE * 1024 * HID * 2;
  u16* wdT   = (u16*)ws;  ws += (size_t)NE * HID * ISZ * 2;
  u16* actb  = (u16*)ws;  ws += (size_t)NE * ECAP * ISZ * 2;
  int* btok  = (int*)ws;  ws += (size_t)8 * ECAP * 4;
  float* bwp = (float*)ws; ws += (size_t)8 * ECAP * 4;
  int* counts = (int*)ws;

  k_zero_counts<<<1, 64, 0, stream>>>(counts);
  k_cvt_x<<<(T_TOK * HID / 4 + 255) / 256, 256, 0, stream>>>(x, xb, T_TOK * HID / 4);
  k_cvt_wgup<<<dim3(32, 32, NE), dim3(32, 8), 0, stream>>>(wgu, wsg, wgupT);
  k_cvt_wdown<<<dim3(32, 16, NE), dim3(32, 8), 0, stream>>>(wdn, wsd, wdT);
  k_router<<<T_TOK, 64, 0, stream>>>(x, wg, counts, btok, bwp);
  k_gemm_gu<<<dim3(ECAP / BM, 1024 / BN, NE), 256, 0, stream>>>(
      xb, wgupT, counts, btok, bwp, actb);
  k_gemm_down_s<<<dim3(T_TOK / BM, HID / BN), 256, 0, stream>>>(actb, wdT, out);
  k_gemm_down_r<<<dim3(ECAP / BM, HID / BN, 8), 256, 0, stream>>>(
      actb, wdT, counts, btok, out);
}

// Round 3
// 263.813 us; speedup vs baseline: 1.6544x; 1.6544x over previous
//
#include <hip/hip_runtime.h>
#include <hip/hip_bf16.h>
#include <cstdint>

#define T_TOK 8192
#define HID   1024
#define NE    9      // 8 routed experts + 1 shared
#define ISZ   512
#define RBASE 17408  // routed slot space: 16384 + 8*128 padding; shared rows at [RBASE, RBASE+8192)
#define NSLOT (RBASE + T_TOK)

#define BM 128
#define BN 128
#define BK 32

typedef unsigned short u16;
typedef unsigned int   u32;
typedef __attribute__((ext_vector_type(8))) short short8;
typedef __attribute__((ext_vector_type(4))) float f32x4;

__device__ __forceinline__ u16 f2bf(float f) {
  u32 u = __builtin_bit_cast(u32, f);
  return (u16)((u + 0x7fffu + ((u >> 16) & 1u)) >> 16);
}
__device__ __forceinline__ float bf2f(u16 v) {
  return __builtin_bit_cast(float, (u32)v << 16);
}

#define STAGE(gp, lp) __builtin_amdgcn_global_load_lds( \
    (__attribute__((address_space(1))) u32*)(gp),       \
    (__attribute__((address_space(3))) u32*)(lp), 16, 0, 0)

// ---------------- conversions ----------------
__global__ void k_cvt_x(const float* __restrict__ x, u16* __restrict__ xb, int n4) {
  int i = blockIdx.x * blockDim.x + threadIdx.x;
  if (i >= n4) return;
  float4 v = ((const float4*)x)[i];
  ushort4 o;
  o.x = f2bf(v.x); o.y = f2bf(v.y); o.z = f2bf(v.z); o.w = f2bf(v.w);
  ((ushort4*)xb)[i] = o;
}

// w_experts_gate_up [8][1024][1024] + w_shared_gate_up [1024][1024]
// -> dst [9][1024(colp)][1024(h)]  (transposed, gate/up interleaved per 16 cols)
__global__ void k_cvt_wgup(const float* __restrict__ wexp, const float* __restrict__ wsh,
                           u16* __restrict__ dst) {
  __shared__ float tile[32][33];
  const int e = blockIdx.z;
  const float* src = (e < 8) ? (wexp + (size_t)e * HID * 1024) : wsh;
  const int c0 = blockIdx.x * 32, h0 = blockIdx.y * 32;
  const int tx = threadIdx.x, ty = threadIdx.y;
  for (int i = ty; i < 32; i += 8)
    tile[i][tx] = src[(size_t)(h0 + i) * 1024 + c0 + tx];   // tile[h_loc][c_loc]
  __syncthreads();
  for (int j = ty; j < 32; j += 8) {
    int c = c0 + j;
    int i = (c < 512) ? c : (c - 512);
    int colp = ((i >> 4) * 32) + ((c < 512) ? 0 : 16) + (i & 15);
    dst[((size_t)e * 1024 + colp) * HID + h0 + tx] = f2bf(tile[tx][j]);
  }
}

// w_experts_down [8][512][1024] + w_shared_down [512][1024]
// -> dst [9][1024(h_out)][512(i)]  (transposed)
__global__ void k_cvt_wdown(const float* __restrict__ wexp, const float* __restrict__ wsh,
                            u16* __restrict__ dst) {
  __shared__ float tile[32][33];
  const int e = blockIdx.z;
  const float* src = (e < 8) ? (wexp + (size_t)e * ISZ * HID) : wsh;
  const int h0 = blockIdx.x * 32, i0 = blockIdx.y * 32;
  const int tx = threadIdx.x, ty = threadIdx.y;
  for (int a = ty; a < 32; a += 8)
    tile[a][tx] = src[(size_t)(i0 + a) * HID + h0 + tx];    // tile[i_loc][h_loc]
  __syncthreads();
  for (int j = ty; j < 32; j += 8)
    dst[((size_t)e * HID + h0 + j) * ISZ + i0 + tx] = f2bf(tile[tx][j]);
}

// ---------------- router phase A: per-token top-2, no atomics ----------------
__global__ __launch_bounds__(256) void k_router(
    const float* __restrict__ x, const float* __restrict__ wg,
    int* __restrict__ eidx, float2* __restrict__ wts) {
  const int t = blockIdx.x * 4 + (threadIdx.x >> 6);
  const int l = threadIdx.x & 63;
  float a[8] = {0, 0, 0, 0, 0, 0, 0, 0};
  const float* xr = x + (size_t)t * HID;
#pragma unroll
  for (int j = 0; j < HID / 64; ++j) {
    const int h = j * 64 + l;
    const float xv = xr[h];
    const float4 w0 = *(const float4*)&wg[h * 8];
    const float4 w1 = *(const float4*)&wg[h * 8 + 4];
    a[0] += xv * w0.x; a[1] += xv * w0.y; a[2] += xv * w0.z; a[3] += xv * w0.w;
    a[4] += xv * w1.x; a[5] += xv * w1.y; a[6] += xv * w1.z; a[7] += xv * w1.w;
  }
#pragma unroll
  for (int off = 32; off >= 1; off >>= 1) {
#pragma unroll
    for (int e2 = 0; e2 < 8; ++e2) a[e2] += __shfl_xor(a[e2], off);
  }
  if (l == 0) {
    int ia = 0;
#pragma unroll
    for (int e2 = 1; e2 < 8; ++e2) if (a[e2] > a[ia]) ia = e2;
    int ib = (ia == 0) ? 1 : 0;
#pragma unroll
    for (int e2 = 0; e2 < 8; ++e2) if (e2 != ia && a[e2] > a[ib]) ib = e2;
    float wa = 1.f / (1.f + expf(a[ib] - a[ia]));  // renormalized softmax top-2
    eidx[t] = ia | (ib << 8);
    wts[t] = make_float2(wa, 1.f - wa);
  }
}

// ---------------- router phase B: deterministic counting scatter ----------------
// 1 block, 8 waves; wave e owns expert e. Token-ordered buckets, 128-aligned segments.
__global__ __launch_bounds__(512) void k_scatter(
    const int* __restrict__ eidx, const float2* __restrict__ wts,
    int* __restrict__ btok, float* __restrict__ bw, int* __restrict__ slotmap,
    int* __restrict__ seg, int* __restrict__ segcnt) {
  __shared__ int cnt_s[8];
  __shared__ int goff_s[9];
  const int e = threadIdx.x >> 6;
  const int l = threadIdx.x & 63;

  int c1 = 0;
  for (int c = 0; c < T_TOK / 64; ++c) {
    int v = eidx[c * 64 + l];
    c1 += __popcll(__ballot((v & 255) == e)) + __popcll(__ballot(((v >> 8) & 255) == e));
  }
  if (l == 0) cnt_s[e] = c1;
  __syncthreads();
  if (threadIdx.x == 0) {
    int off = 0;
    for (int k = 0; k < 8; ++k) { goff_s[k] = off; off += (cnt_s[k] + 127) & ~127; }
    goff_s[8] = off;
  }
  __syncthreads();
  const int base0 = goff_s[e];
  const int cnt_e = cnt_s[e];
  const unsigned long long below = (l == 63) ? ~0ull >> 1 : ((1ull << l) - 1);

  int base = base0;
  for (int c = 0; c < T_TOK / 64; ++c) {
    const int t = c * 64 + l;
    const int v = eidx[t];
    const float2 wv = wts[t];
    const unsigned long long ma = __ballot((v & 255) == e);
    const unsigned long long mb = __ballot(((v >> 8) & 255) == e);
    if ((v & 255) == e) {
      int s = base + __popcll(ma & below);
      btok[s] = t; bw[s] = wv.x; slotmap[2 * t] = s;
    }
    if (((v >> 8) & 255) == e) {
      int s = base + __popcll(ma) + __popcll(mb & below);
      btok[s] = t; bw[s] = wv.y; slotmap[2 * t + 1] = s;
    }
    base += __popcll(ma) + __popcll(mb);
  }
  for (int p = cnt_e + l; p < ((cnt_e + 127) & ~127); p += 64) {
    btok[base0 + p] = 0; bw[base0 + p] = 0.f;
  }
  if (threadIdx.x < 9) seg[threadIdx.x] = goff_s[threadIdx.x];
  if (threadIdx.x < 8) segcnt[threadIdx.x] = cnt_s[threadIdx.x];
}

// ---------------- segment lookup ----------------
__device__ __forceinline__ bool seg_lookup(const int* __restrict__ seg,
                                           const int* __restrict__ segcnt,
                                           int brow, int& e) {
  if (brow >= RBASE) { e = 8; return true; }
  if (brow >= seg[8]) return false;
  e = 0;
#pragma unroll
  for (int k = 1; k < 8; ++k) if (brow >= seg[k]) e = k;
  return brow < seg[e] + segcnt[e];
}

// ---------------- GEMM1: act[slot] = silu(g)*u * w  (A gathered by token) -------
__global__ __launch_bounds__(256) void k_gemm_gu(
    const u16* __restrict__ xb,     // [T][H] bf16
    const u16* __restrict__ wgupT,  // [NE][1024][H] bf16 (B^T, interleaved cols)
    const int* __restrict__ seg, const int* __restrict__ segcnt,
    const int* __restrict__ btok, const float* __restrict__ bw,
    u16* __restrict__ act)          // [NSLOT][ISZ] bf16 (pre-scaled)
{
  const int brow = blockIdx.x * BM;
  int e;
  if (!seg_lookup(seg, segcnt, brow, e)) return;

  __shared__ __align__(16) u16 As[BM * BK];
  __shared__ __align__(16) u16 Bs[BN * BK];
  __shared__ float cws[BM];

  const int tid = threadIdx.x;
  const int w = tid >> 6, l = tid & 63;
  const int bcol = blockIdx.y * BN;

  if (tid < BM) cws[tid] = (e < 8) ? bw[brow + tid] : 1.f;

  const int sub = l >> 2;        // row within 16-row chunk
  const int kc  = (l & 3) * 8;   // k element offset

  const int gs0 = brow + (w * 2 + 0) * 16 + sub;
  const int gs1 = brow + (w * 2 + 1) * 16 + sub;
  const int t0 = (e < 8) ? btok[gs0] : (gs0 - RBASE);
  const int t1 = (e < 8) ? btok[gs1] : (gs1 - RBASE);

  const u16* ga0 = xb + (size_t)t0 * HID + kc;
  const u16* ga1 = xb + (size_t)t1 * HID + kc;
  const u16* gb0 = wgupT + ((size_t)e * 1024 + bcol + (w * 2 + 0) * 16 + sub) * HID + kc;
  const u16* gb1 = wgupT + ((size_t)e * 1024 + bcol + (w * 2 + 1) * 16 + sub) * HID + kc;

  u16* la0 = &As[(w * 2 + 0) * 16 * BK];
  u16* la1 = &As[(w * 2 + 1) * 16 * BK];
  u16* lb0 = &Bs[(w * 2 + 0) * 16 * BK];
  u16* lb1 = &Bs[(w * 2 + 1) * 16 * BK];

  const int wm = w >> 1, wn = w & 1;
  const int fr = l & 15, fg = l >> 4;

  f32x4 acc[4][4];
#pragma unroll
  for (int m = 0; m < 4; ++m)
#pragma unroll
    for (int n = 0; n < 4; ++n) acc[m][n] = (f32x4){0.f, 0.f, 0.f, 0.f};

  for (int kt = 0; kt < HID / BK; ++kt) {
    const int ko = kt * BK;
    STAGE(ga0 + ko, la0);
    STAGE(ga1 + ko, la1);
    STAGE(gb0 + ko, lb0);
    STAGE(gb1 + ko, lb1);
    __syncthreads();
    short8 af[4], bfr[4];
#pragma unroll
    for (int m = 0; m < 4; ++m)
      af[m] = *(const short8*)&As[(wm * 64 + m * 16 + fr) * BK + fg * 8];
#pragma unroll
    for (int n = 0; n < 4; ++n)
      bfr[n] = *(const short8*)&Bs[(wn * 64 + n * 16 + fr) * BK + fg * 8];
#pragma unroll
    for (int m = 0; m < 4; ++m)
#pragma unroll
      for (int n = 0; n < 4; ++n)
        acc[m][n] = __builtin_amdgcn_mfma_f32_16x16x32_bf16(af[m], bfr[n], acc[m][n], 0, 0, 0);
    __syncthreads();
  }

#pragma unroll
  for (int m = 0; m < 4; ++m) {
#pragma unroll
    for (int p = 0; p < 2; ++p) {
      f32x4 g = acc[m][2 * p], u = acc[m][2 * p + 1];
      const int col = (blockIdx.y * 4 + wn * 2 + p) * 16 + fr;
#pragma unroll
      for (int r = 0; r < 4; ++r) {
        const int row_l = wm * 64 + m * 16 + fg * 4 + r;
        float gate = g[r], u2 = u[r];
        float s = gate / (1.f + expf(-gate));
        act[(size_t)(brow + row_l) * ISZ + col] = f2bf(s * u2 * cws[row_l]);
      }
    }
  }
}

// ---------------- GEMM2 core (K = 512) ----------------
template <bool SHARED>
__device__ __forceinline__ void gemm_down_body(
    const u16* __restrict__ act, const u16* __restrict__ wdT,
    void* __restrict__ dst, int e, int brow, int bcol) {
  __shared__ __align__(16) u16 As[BM * BK];
  __shared__ __align__(16) u16 Bs[BN * BK];

  const int tid = threadIdx.x;
  const int w = tid >> 6, l = tid & 63;
  const int sub = l >> 2;
  const int kc  = (l & 3) * 8;

  const u16* pa0 = act + (size_t)(brow + (w * 2 + 0) * 16 + sub) * ISZ + kc;
  const u16* pa1 = act + (size_t)(brow + (w * 2 + 1) * 16 + sub) * ISZ + kc;
  const u16* pb0 = wdT + ((size_t)e * HID + bcol + (w * 2 + 0) * 16 + sub) * ISZ + kc;
  const u16* pb1 = wdT + ((size_t)e * HID + bcol + (w * 2 + 1) * 16 + sub) * ISZ + kc;

  u16* la0 = &As[(w * 2 + 0) * 16 * BK];
  u16* la1 = &As[(w * 2 + 1) * 16 * BK];
  u16* lb0 = &Bs[(w * 2 + 0) * 16 * BK];
  u16* lb1 = &Bs[(w * 2 + 1) * 16 * BK];

  const int wm = w >> 1, wn = w & 1;
  const int fr = l & 15, fg = l >> 4;

  f32x4 acc[4][4];
#pragma unroll
  for (int m = 0; m < 4; ++m)
#pragma unroll
    for (int n = 0; n < 4; ++n) acc[m][n] = (f32x4){0.f, 0.f, 0.f, 0.f};

  for (int kt = 0; kt < ISZ / BK; ++kt) {   // 16 iters
    const int ko = kt * BK;
    STAGE(pa0 + ko, la0);
    STAGE(pa1 + ko, la1);
    STAGE(pb0 + ko, lb0);
    STAGE(pb1 + ko, lb1);
    __syncthreads();
    short8 af[4], bfr[4];
#pragma unroll
    for (int m = 0; m < 4; ++m)
      af[m] = *(const short8*)&As[(wm * 64 + m * 16 + fr) * BK + fg * 8];
#pragma unroll
    for (int n = 0; n < 4; ++n)
      bfr[n] = *(const short8*)&Bs[(wn * 64 + n * 16 + fr) * BK + fg * 8];
#pragma unroll
    for (int m = 0; m < 4; ++m)
#pragma unroll
      for (int n = 0; n < 4; ++n)
        acc[m][n] = __builtin_amdgcn_mfma_f32_16x16x32_bf16(af[m], bfr[n], acc[m][n], 0, 0, 0);
    __syncthreads();
  }

#pragma unroll
  for (int m = 0; m < 4; ++m) {
#pragma unroll
    for (int r = 0; r < 4; ++r) {
      const int row = brow + wm * 64 + m * 16 + fg * 4 + r;
#pragma unroll
      for (int n = 0; n < 4; ++n) {
        const int col = bcol + wn * 64 + n * 16 + fr;
        if (SHARED)
          ((float*)dst)[(size_t)(row - RBASE) * HID + col] = acc[m][n][r];
        else
          ((u16*)dst)[(size_t)row * HID + col] = f2bf(acc[m][n][r]);
      }
    }
  }
}

__global__ __launch_bounds__(256) void k_gemm_down_s(
    const u16* __restrict__ act, const u16* __restrict__ wdT, float* __restrict__ out) {
  gemm_down_body<true>(act, wdT, out, 8, RBASE + blockIdx.x * BM, blockIdx.y * BN);
}

__global__ __launch_bounds__(256) void k_gemm_down_r(
    const u16* __restrict__ act, const u16* __restrict__ wdT,
    const int* __restrict__ seg, const int* __restrict__ segcnt,
    u16* __restrict__ tmp) {
  const int brow = blockIdx.x * BM;
  int e;
  if (!seg_lookup(seg, segcnt, brow, e)) return;
  gemm_down_body<false>(act, wdT, tmp, e, brow, blockIdx.y * BN);
}

// ---------------- combine: out[t] += tmp[slot0] + tmp[slot1] ----------------
__global__ __launch_bounds__(256) void k_combine(
    const u16* __restrict__ tmp, const int* __restrict__ slotmap,
    float* __restrict__ out) {
  const int idx = blockIdx.x * 256 + threadIdx.x;
  const int t = idx >> 7;
  const int c = (idx & 127) << 3;
  const int s0 = slotmap[2 * t], s1 = slotmap[2 * t + 1];
  const short8 a = *(const short8*)(tmp + (size_t)s0 * HID + c);
  const short8 b = *(const short8*)(tmp + (size_t)s1 * HID + c);
  float* po = out + (size_t)t * HID + c;
  float4 o0 = *(float4*)po, o1 = *(float4*)(po + 4);
  float r[8] = {o0.x, o0.y, o0.z, o0.w, o1.x, o1.y, o1.z, o1.w};
#pragma unroll
  for (int j = 0; j < 8; ++j) r[j] += bf2f((u16)a[j]) + bf2f((u16)b[j]);
  *(float4*)po       = make_float4(r[0], r[1], r[2], r[3]);
  *(float4*)(po + 4) = make_float4(r[4], r[5], r[6], r[7]);
}

// ---------------- launch ----------------
extern "C" void kernel_launch(void* const* d_in, const int* in_sizes, int n_in,
                              void* d_out, int out_size, void* d_ws, size_t ws_size,
                              hipStream_t stream) {
  const float* x   = (const float*)d_in[0];
  const float* wg  = (const float*)d_in[1];
  const float* wgu = (const float*)d_in[2];
  const float* wdn = (const float*)d_in[3];
  const float* wsg = (const float*)d_in[4];
  const float* wsd = (const float*)d_in[5];
  float* out = (float*)d_out;

  char* ws = (char*)d_ws;
  u16* xb    = (u16*)ws;  ws += (size_t)T_TOK * HID * 2;
  u16* wgupT = (u16*)ws;  ws += (size_t)NE * 1024 * HID * 2;
  u16* wdT   = (u16*)ws;  ws += (size_t)NE * HID * ISZ * 2;
  u16* actb  = (u16*)ws;  ws += (size_t)NSLOT * ISZ * 2;
  u16* tmp   = (u16*)ws;  ws += (size_t)RBASE * HID * 2;
  int* eidx  = (int*)ws;  ws += (size_t)T_TOK * 4;
  float2* wt = (float2*)ws; ws += (size_t)T_TOK * 8;
  int* btok  = (int*)ws;  ws += (size_t)RBASE * 4;
  float* bwp = (float*)ws; ws += (size_t)RBASE * 4;
  int* smap  = (int*)ws;  ws += (size_t)2 * T_TOK * 4;
  int* seg   = (int*)ws;  ws += 16 * 4;
  int* segc  = (int*)ws;

  k_cvt_x<<<(T_TOK * HID / 4 + 255) / 256, 256, 0, stream>>>(x, xb, T_TOK * HID / 4);
  k_cvt_wgup<<<dim3(32, 32, NE), dim3(32, 8), 0, stream>>>(wgu, wsg, wgupT);
  k_cvt_wdown<<<dim3(32, 16, NE), dim3(32, 8), 0, stream>>>(wdn, wsd, wdT);
  k_router<<<T_TOK / 4, 256, 0, stream>>>(x, wg, eidx, wt);
  k_scatter<<<1, 512, 0, stream>>>(eidx, wt, btok, bwp, smap, seg, segc);
  k_gemm_gu<<<dim3(NSLOT / BM, 1024 / BN), 256, 0, stream>>>(
      xb, wgupT, seg, segc, btok, bwp, actb);
  k_gemm_down_s<<<dim3(T_TOK / BM, HID / BN), 256, 0, stream>>>(actb, wdT, out);
  k_gemm_down_r<<<dim3(RBASE / BM, HID / BN), 256, 0, stream>>>(actb, wdT, seg, segc, tmp);
  k_combine<<<(T_TOK * HID / 8) / 256, 256, 0, stream>>>(tmp, smap, out);
}